// Round 1
// baseline (461.611 us; speedup 1.0000x reference)
//
#include <hip/hip_runtime.h>
#include <hip/hip_bf16.h>

#define SREF 2048
#define DHEAD 128
#define QBLK 64
#define KVBLK 64
#define NWAVE 4
#define NTHREADS 256
#define KSTR 136   // ushorts per K-row in LDS (272B, 16B-aligned, bank-spread)
#define VSTR 72    // ushorts per VT-row in LDS (144B, 16B-aligned)
#define PSTR 72

typedef short bf16x8 __attribute__((ext_vector_type(8)));
typedef float f32x4 __attribute__((ext_vector_type(4)));

__device__ __forceinline__ ushort f2bf(float x) {
    unsigned u = __builtin_bit_cast(unsigned, x);
    u += 0x7fffu + ((u >> 16) & 1u);   // round-to-nearest-even
    return (ushort)(u >> 16);
}

__global__ __launch_bounds__(NTHREADS) void attn_fwd_kernel(
    const float* __restrict__ Q, const float* __restrict__ K,
    const float* __restrict__ V, float* __restrict__ O)
{
    __shared__ ushort Ksh[KVBLK * KSTR];        // K[key][d] bf16
    __shared__ ushort Vsh[DHEAD * VSTR];        // V^T[d][key] bf16
    __shared__ ushort Psh[NWAVE][16 * PSTR];    // per-wave P[q][key] bf16

    const int t    = threadIdx.x;
    const int lane = t & 63;
    const int wv   = t >> 6;
    const int lq   = lane & 15;   // A-row / C-col index
    const int kh   = lane >> 4;   // k-chunk group 0..3

    const int bh = blockIdx.y;
    const int q0 = blockIdx.x * QBLK;
    const size_t base = (size_t)bh * SREF * DHEAD;

    // ---- Q fragments in registers, pre-scaled by 1/sqrt(dk) ----
    const float scale = 0.08838834764831845f;
    bf16x8 qf[4];
    {
        const float* qrow = Q + base + (size_t)(q0 + wv * 16 + lq) * DHEAD;
        #pragma unroll
        for (int kk = 0; kk < 4; ++kk) {
            const int d0 = kk * 32 + kh * 8;
            float4 a = *(const float4*)(qrow + d0);
            float4 b = *(const float4*)(qrow + d0 + 4);
            bf16x8 f;
            f[0] = (short)f2bf(a.x * scale); f[1] = (short)f2bf(a.y * scale);
            f[2] = (short)f2bf(a.z * scale); f[3] = (short)f2bf(a.w * scale);
            f[4] = (short)f2bf(b.x * scale); f[5] = (short)f2bf(b.y * scale);
            f[6] = (short)f2bf(b.z * scale); f[7] = (short)f2bf(b.w * scale);
            qf[kk] = f;
        }
    }

    // ---- online softmax state (rows q = kh*4 + r, matching C/D layout) ----
    float mrun[4], lrun[4];
    f32x4 acc_o[8];
    #pragma unroll
    for (int r = 0; r < 4; ++r) { mrun[r] = -1e30f; lrun[r] = 0.0f; }
    #pragma unroll
    for (int db = 0; db < 8; ++db) acc_o[db] = (f32x4){0.f, 0.f, 0.f, 0.f};

    for (int kv0 = 0; kv0 < SREF; kv0 += KVBLK) {
        __syncthreads();   // all waves done reading previous tile

        // ---- stage K tile: bf16, row-major, coalesced float4 loads ----
        const float* kbase = K + base + (size_t)kv0 * DHEAD;
        #pragma unroll
        for (int i = 0; i < 8; ++i) {
            const int idx = t + i * NTHREADS;
            const int row = idx >> 5;
            const int c4  = idx & 31;
            float4 f = *(const float4*)(kbase + row * DHEAD + c4 * 4);
            ushort4 h;
            h.x = f2bf(f.x); h.y = f2bf(f.y); h.z = f2bf(f.z); h.w = f2bf(f.w);
            *(ushort4*)&Ksh[row * KSTR + c4 * 4] = h;
        }
        // ---- stage V tile transposed: VT[d][key] ----
        const float* vbase = V + base + (size_t)kv0 * DHEAD;
        #pragma unroll
        for (int i = 0; i < 8; ++i) {
            const int key = (t & 31) + 32 * (i & 1);
            const int d4  = (t >> 5) + 8 * (i >> 1);
            float4 f = *(const float4*)(vbase + key * DHEAD + d4 * 4);
            Vsh[(d4 * 4 + 0) * VSTR + key] = f2bf(f.x);
            Vsh[(d4 * 4 + 1) * VSTR + key] = f2bf(f.y);
            Vsh[(d4 * 4 + 2) * VSTR + key] = f2bf(f.z);
            Vsh[(d4 * 4 + 3) * VSTR + key] = f2bf(f.w);
        }
        __syncthreads();

        // ---- S = Q K^T (scaled): 16 MFMAs ----
        f32x4 accs[4];
        #pragma unroll
        for (int nb = 0; nb < 4; ++nb) accs[nb] = (f32x4){0.f, 0.f, 0.f, 0.f};
        #pragma unroll
        for (int kk = 0; kk < 4; ++kk) {
            #pragma unroll
            for (int nb = 0; nb < 4; ++nb) {
                bf16x8 kf = *(const bf16x8*)&Ksh[(nb * 16 + lq) * KSTR + kk * 32 + kh * 8];
                accs[nb] = __builtin_amdgcn_mfma_f32_16x16x32_bf16(qf[kk], kf, accs[nb], 0, 0, 0);
            }
        }

        // ---- online softmax (wave-parallel; rows live on 16-lane groups) ----
        float ps[4][4];
        #pragma unroll
        for (int r = 0; r < 4; ++r) {
            float v = fmaxf(fmaxf(accs[0][r], accs[1][r]), fmaxf(accs[2][r], accs[3][r]));
            #pragma unroll
            for (int mk = 1; mk < 16; mk <<= 1) v = fmaxf(v, __shfl_xor(v, mk));
            const float mnew  = fmaxf(mrun[r], v);
            const float alpha = __expf(mrun[r] - mnew);
            mrun[r] = mnew;
            float rs = 0.0f;
            #pragma unroll
            for (int nb = 0; nb < 4; ++nb) {
                const float p = __expf(accs[nb][r] - mnew);
                ps[nb][r] = p;
                rs += p;
            }
            #pragma unroll
            for (int mk = 1; mk < 16; mk <<= 1) rs += __shfl_xor(rs, mk);
            lrun[r] = lrun[r] * alpha + rs;
            #pragma unroll
            for (int db = 0; db < 8; ++db) acc_o[db][r] *= alpha;
        }

        // ---- P -> LDS (per-wave private; wave-internal visibility only) ----
        #pragma unroll
        for (int nb = 0; nb < 4; ++nb)
            #pragma unroll
            for (int r = 0; r < 4; ++r)
                Psh[wv][(kh * 4 + r) * PSTR + nb * 16 + lq] = f2bf(ps[nb][r]);

        // ---- O += P V : 16 MFMAs ----
        #pragma unroll
        for (int ks = 0; ks < 2; ++ks) {
            bf16x8 pa = *(const bf16x8*)&Psh[wv][lq * PSTR + ks * 32 + kh * 8];
            #pragma unroll
            for (int db = 0; db < 8; ++db) {
                bf16x8 vf = *(const bf16x8*)&Vsh[(db * 16 + lq) * VSTR + ks * 32 + kh * 8];
                acc_o[db] = __builtin_amdgcn_mfma_f32_16x16x32_bf16(pa, vf, acc_o[db], 0, 0, 0);
            }
        }
    }

    // ---- epilogue: O / l ----
    #pragma unroll
    for (int r = 0; r < 4; ++r) {
        const float inv = 1.0f / lrun[r];
        float* orow = O + base + (size_t)(q0 + wv * 16 + kh * 4 + r) * DHEAD;
        #pragma unroll
        for (int db = 0; db < 8; ++db)
            orow[db * 16 + lq] = acc_o[db][r] * inv;
    }
}

extern "C" void kernel_launch(void* const* d_in, const int* in_sizes, int n_in,
                              void* d_out, int out_size, void* d_ws, size_t ws_size,
                              hipStream_t stream) {
    const float* Q = (const float*)d_in[0];
    const float* K = (const float*)d_in[1];
    const float* V = (const float*)d_in[2];
    float* O = (float*)d_out;
    const int BH = in_sizes[0] / (SREF * DHEAD);   // B*H = 32
    dim3 grid(SREF / QBLK, BH);
    attn_fwd_kernel<<<grid, dim3(NTHREADS), 0, stream>>>(Q, K, V, O);
}

// Round 2
// 190.097 us; speedup vs baseline: 2.4283x; 2.4283x over previous
//
#include <hip/hip_runtime.h>
#include <hip/hip_bf16.h>

#define SREF 2048
#define DHEAD 128
#define QBLK 64
#define KVBLK 64
#define NWAVE 4
#define NTHREADS 256
#define NTILES (SREF / KVBLK)
#define PSTR 72
#define QSCALE 0.12751743f   /* log2(e)/sqrt(128) */

typedef short bf16x8 __attribute__((ext_vector_type(8)));
typedef float f32x4 __attribute__((ext_vector_type(4)));

typedef const __attribute__((address_space(1))) void* gas_t;
typedef __attribute__((address_space(3))) void* las_t;

__device__ __forceinline__ ushort f2bf(float x) {
    unsigned u = __builtin_bit_cast(unsigned, x);
    u += 0x7fffu + ((u >> 16) & 1u);   // round-to-nearest-even
    return (ushort)(u >> 16);
}

__device__ __forceinline__ float fexp2(float x) {
#if __has_builtin(__builtin_amdgcn_exp2f)
    return __builtin_amdgcn_exp2f(x);
#else
    return exp2f(x);
#endif
}

// ---------------- precompute: K -> bf16, V -> V^T bf16 ----------------
__global__ __launch_bounds__(NTHREADS) void preconv_kernel(
    const float* __restrict__ K, const float* __restrict__ V,
    ushort* __restrict__ Kb, ushort* __restrict__ VTb)
{
    __shared__ ushort T[DHEAD * PSTR];   // V^T tile [d][key], padded

    const int t  = threadIdx.x;
    const int bh = blockIdx.y;
    const int s0 = blockIdx.x * KVBLK;
    const size_t base = (size_t)bh * SREF * DHEAD;

    // K: straight fp32 -> bf16, coalesced
    const float* kb = K + base + (size_t)s0 * DHEAD;
    ushort* kout = Kb + base + (size_t)s0 * DHEAD;
    #pragma unroll
    for (int i = 0; i < 8; ++i) {
        int idx = t + i * NTHREADS;
        float4 f = *(const float4*)(kb + idx * 4);
        ushort4 h; h.x = f2bf(f.x); h.y = f2bf(f.y); h.z = f2bf(f.z); h.w = f2bf(f.w);
        *(ushort4*)(kout + idx * 4) = h;
    }

    // V: transpose via LDS (write T[d][key], 2-way banks = free)
    const float* vb = V + base + (size_t)s0 * DHEAD;
    #pragma unroll
    for (int i = 0; i < 8; ++i) {
        const int key = (t & 31) + 32 * (i & 1);
        const int d4  = (t >> 5) + 8 * (i >> 1);
        float4 f = *(const float4*)(vb + key * DHEAD + d4 * 4);
        T[(d4 * 4 + 0) * PSTR + key] = f2bf(f.x);
        T[(d4 * 4 + 1) * PSTR + key] = f2bf(f.y);
        T[(d4 * 4 + 2) * PSTR + key] = f2bf(f.z);
        T[(d4 * 4 + 3) * PSTR + key] = f2bf(f.w);
    }
    __syncthreads();

    // write VT[bh][d][s0..s0+64), 16B coalesced stores
    ushort* vt = VTb + (size_t)bh * DHEAD * SREF + s0;
    #pragma unroll
    for (int i = 0; i < 4; ++i) {
        int idx = t + i * NTHREADS;      // 0..1023
        int d = idx >> 3;
        int c = (idx & 7) * 8;
        bf16x8 v = *(const bf16x8*)&T[d * PSTR + c];
        *(bf16x8*)(vt + (size_t)d * SREF + c) = v;
    }
}

// ---------------- main attention kernel ----------------
__global__ __launch_bounds__(NTHREADS) void attn_fwd_kernel(
    const float* __restrict__ Q, const ushort* __restrict__ Kb,
    const ushort* __restrict__ VTb, float* __restrict__ O)
{
    __shared__ ushort Ksh[2][KVBLK * DHEAD];   // 2 x 16 KB, linear+src-swizzled
    __shared__ ushort Vsh[2][DHEAD * KVBLK];   // 2 x 16 KB (V^T tile)
    __shared__ ushort Psh[NWAVE][16 * PSTR];   // per-wave P round-trip

    const int t    = threadIdx.x;
    const int lane = t & 63;
    const int wv   = t >> 6;
    const int lq   = lane & 15;
    const int kh   = lane >> 4;

    const int bh = blockIdx.y;
    const int q0 = blockIdx.x * QBLK;
    const size_t base = (size_t)bh * SREF * DHEAD;

    // ---- Q fragments (pre-scaled into log2 domain) ----
    bf16x8 qf[4];
    {
        const float* qrow = Q + base + (size_t)(q0 + wv * 16 + lq) * DHEAD;
        #pragma unroll
        for (int kk = 0; kk < 4; ++kk) {
            const int d0 = kk * 32 + kh * 8;
            float4 a = *(const float4*)(qrow + d0);
            float4 b = *(const float4*)(qrow + d0 + 4);
            bf16x8 f;
            f[0] = (short)f2bf(a.x * QSCALE); f[1] = (short)f2bf(a.y * QSCALE);
            f[2] = (short)f2bf(a.z * QSCALE); f[3] = (short)f2bf(a.w * QSCALE);
            f[4] = (short)f2bf(b.x * QSCALE); f[5] = (short)f2bf(b.y * QSCALE);
            f[6] = (short)f2bf(b.z * QSCALE); f[7] = (short)f2bf(b.w * QSCALE);
            qf[kk] = f;
        }
    }

    const char* ksrcb = (const char*)(Kb + base);
    const char* vsrcb = (const char*)(VTb + (size_t)bh * DHEAD * SREF);

// stage one KV tile into buffer b: 8 global_load_lds x16B per thread,
// global source pre-swizzled so swizzled ds_reads are conflict-free (T2/m173)
#define STAGE(b, kv0) do {                                                      \
    const char* kt_ = ksrcb + (size_t)(kv0) * (DHEAD * 2);                      \
    const char* vt_ = vsrcb + (size_t)(kv0) * 2;                                \
    _Pragma("unroll")                                                           \
    for (int i_ = 0; i_ < 4; ++i_) {                                            \
        int L_ = wv * 1024 + lane * 16 + i_ * 4096;                             \
        int r_ = L_ >> 8;                                                       \
        int s_ = L_ ^ ((r_ & 7) << 4);                                          \
        __builtin_amdgcn_global_load_lds((gas_t)(const void*)(kt_ + s_),        \
            (las_t)(void*)((char*)&Ksh[b][0] + wv * 1024 + i_ * 4096),          \
            16, 0, 0);                                                          \
    }                                                                           \
    _Pragma("unroll")                                                           \
    for (int i_ = 0; i_ < 4; ++i_) {                                            \
        int L_ = wv * 1024 + lane * 16 + i_ * 4096;                             \
        int r_ = L_ >> 7;                                                       \
        int c_ = L_ & 127;                                                      \
        int s_ = c_ ^ ((r_ & 7) << 4);                                          \
        __builtin_amdgcn_global_load_lds(                                       \
            (gas_t)(const void*)(vt_ + (size_t)r_ * (SREF * 2) + s_),           \
            (las_t)(void*)((char*)&Vsh[b][0] + wv * 1024 + i_ * 4096),          \
            16, 0, 0);                                                          \
    }                                                                           \
} while (0)

    float mrun[4], lrun[4];
    f32x4 acc_o[8];
    #pragma unroll
    for (int r = 0; r < 4; ++r) { mrun[r] = -1e30f; lrun[r] = 0.0f; }
    #pragma unroll
    for (int db = 0; db < 8; ++db) acc_o[db] = (f32x4){0.f, 0.f, 0.f, 0.f};

    STAGE(0, 0);
    int buf = 0;

    for (int tt = 0; tt < NTILES; ++tt) {
        if (tt + 1 < NTILES) {
            STAGE(buf ^ 1, (tt + 1) * KVBLK);
            asm volatile("s_waitcnt vmcnt(8)" ::: "memory");  // current tile done, next in flight
        } else {
            asm volatile("s_waitcnt vmcnt(0)" ::: "memory");
        }
        __builtin_amdgcn_s_barrier();
        __builtin_amdgcn_sched_barrier(0);

        // ---- S = Q K^T (log2 domain) ----
        f32x4 accs[4];
        #pragma unroll
        for (int nb = 0; nb < 4; ++nb) accs[nb] = (f32x4){0.f, 0.f, 0.f, 0.f};
        #pragma unroll
        for (int kk = 0; kk < 4; ++kk) {
            #pragma unroll
            for (int nb = 0; nb < 4; ++nb) {
                int A = (nb * 16 + lq) * 256 + kk * 64 + kh * 16;   // logical byte
                const bf16x8 kf = *(const bf16x8*)((const char*)&Ksh[buf][0] + (A ^ ((lq & 7) << 4)));
                accs[nb] = __builtin_amdgcn_mfma_f32_16x16x32_bf16(qf[kk], kf, accs[nb], 0, 0, 0);
            }
        }

        // ---- online softmax (base-2), wave-parallel over 16-lane groups ----
        float ps[4][4];
        #pragma unroll
        for (int r = 0; r < 4; ++r) {
            float v = fmaxf(fmaxf(accs[0][r], accs[1][r]), fmaxf(accs[2][r], accs[3][r]));
            #pragma unroll
            for (int mk = 1; mk < 16; mk <<= 1) v = fmaxf(v, __shfl_xor(v, mk));
            const float mnew  = fmaxf(mrun[r], v);
            const float alpha = fexp2(mrun[r] - mnew);
            mrun[r] = mnew;
            float rs = 0.0f;
            #pragma unroll
            for (int nb = 0; nb < 4; ++nb) {
                const float p = fexp2(accs[nb][r] - mnew);
                ps[nb][r] = p;
                rs += p;
            }
            #pragma unroll
            for (int mk = 1; mk < 16; mk <<= 1) rs += __shfl_xor(rs, mk);
            lrun[r] = lrun[r] * alpha + rs;
            #pragma unroll
            for (int db = 0; db < 8; ++db) acc_o[db][r] *= alpha;
        }

        // ---- P -> per-wave LDS (wave-private, in-order DS ops) ----
        #pragma unroll
        for (int nb = 0; nb < 4; ++nb)
            #pragma unroll
            for (int r = 0; r < 4; ++r)
                Psh[wv][(kh * 4 + r) * PSTR + nb * 16 + lq] = f2bf(ps[nb][r]);

        // ---- O += P V ----
        #pragma unroll
        for (int ks = 0; ks < 2; ++ks) {
            bf16x8 pa = *(const bf16x8*)&Psh[wv][lq * PSTR + ks * 32 + kh * 8];
            #pragma unroll
            for (int db = 0; db < 8; ++db) {
                int A = (db * 16 + lq) * 128 + ks * 64 + kh * 16;   // logical byte in V^T tile
                const bf16x8 vf = *(const bf16x8*)((const char*)&Vsh[buf][0] + (A ^ ((lq & 7) << 4)));
                acc_o[db] = __builtin_amdgcn_mfma_f32_16x16x32_bf16(pa, vf, acc_o[db], 0, 0, 0);
            }
        }

        __builtin_amdgcn_sched_barrier(0);
        __builtin_amdgcn_s_barrier();   // all waves done reading buf before next STAGE overwrites
        buf ^= 1;
    }

    // ---- epilogue ----
    #pragma unroll
    for (int r = 0; r < 4; ++r) {
        const float inv = 1.0f / lrun[r];
        float* orow = O + base + (size_t)(q0 + wv * 16 + kh * 4 + r) * DHEAD;
        #pragma unroll
        for (int db = 0; db < 8; ++db)
            orow[db * 16 + lq] = acc_o[db][r] * inv;
    }
#undef STAGE
}

// ---------------- fallback (R1 kernel, used only if ws too small) ----------------
__global__ __launch_bounds__(NTHREADS) void attn_fwd_fallback(
    const float* __restrict__ Q, const float* __restrict__ K,
    const float* __restrict__ V, float* __restrict__ O)
{
    __shared__ ushort Ksh[KVBLK * 136];
    __shared__ ushort Vsh[DHEAD * 72];
    __shared__ ushort Psh[NWAVE][16 * PSTR];

    const int t    = threadIdx.x;
    const int lane = t & 63;
    const int wv   = t >> 6;
    const int lq   = lane & 15;
    const int kh   = lane >> 4;

    const int bh = blockIdx.y;
    const int q0 = blockIdx.x * QBLK;
    const size_t base = (size_t)bh * SREF * DHEAD;

    const float scale = 0.08838834764831845f;
    bf16x8 qf[4];
    {
        const float* qrow = Q + base + (size_t)(q0 + wv * 16 + lq) * DHEAD;
        #pragma unroll
        for (int kk = 0; kk < 4; ++kk) {
            const int d0 = kk * 32 + kh * 8;
            float4 a = *(const float4*)(qrow + d0);
            float4 b = *(const float4*)(qrow + d0 + 4);
            bf16x8 f;
            f[0] = (short)f2bf(a.x * scale); f[1] = (short)f2bf(a.y * scale);
            f[2] = (short)f2bf(a.z * scale); f[3] = (short)f2bf(a.w * scale);
            f[4] = (short)f2bf(b.x * scale); f[5] = (short)f2bf(b.y * scale);
            f[6] = (short)f2bf(b.z * scale); f[7] = (short)f2bf(b.w * scale);
            qf[kk] = f;
        }
    }

    float mrun[4], lrun[4];
    f32x4 acc_o[8];
    #pragma unroll
    for (int r = 0; r < 4; ++r) { mrun[r] = -1e30f; lrun[r] = 0.0f; }
    #pragma unroll
    for (int db = 0; db < 8; ++db) acc_o[db] = (f32x4){0.f, 0.f, 0.f, 0.f};

    for (int kv0 = 0; kv0 < SREF; kv0 += KVBLK) {
        __syncthreads();
        const float* kbase = K + base + (size_t)kv0 * DHEAD;
        #pragma unroll
        for (int i = 0; i < 8; ++i) {
            const int idx = t + i * NTHREADS;
            const int row = idx >> 5;
            const int c4  = idx & 31;
            float4 f = *(const float4*)(kbase + row * DHEAD + c4 * 4);
            ushort4 h;
            h.x = f2bf(f.x); h.y = f2bf(f.y); h.z = f2bf(f.z); h.w = f2bf(f.w);
            *(ushort4*)&Ksh[row * 136 + c4 * 4] = h;
        }
        const float* vbase = V + base + (size_t)kv0 * DHEAD;
        #pragma unroll
        for (int i = 0; i < 8; ++i) {
            const int key = (t & 31) + 32 * (i & 1);
            const int d4  = (t >> 5) + 8 * (i >> 1);
            float4 f = *(const float4*)(vbase + key * DHEAD + d4 * 4);
            Vsh[(d4 * 4 + 0) * 72 + key] = f2bf(f.x);
            Vsh[(d4 * 4 + 1) * 72 + key] = f2bf(f.y);
            Vsh[(d4 * 4 + 2) * 72 + key] = f2bf(f.z);
            Vsh[(d4 * 4 + 3) * 72 + key] = f2bf(f.w);
        }
        __syncthreads();

        f32x4 accs[4];
        #pragma unroll
        for (int nb = 0; nb < 4; ++nb) accs[nb] = (f32x4){0.f, 0.f, 0.f, 0.f};
        #pragma unroll
        for (int kk = 0; kk < 4; ++kk) {
            #pragma unroll
            for (int nb = 0; nb < 4; ++nb) {
                bf16x8 kf = *(const bf16x8*)&Ksh[(nb * 16 + lq) * 136 + kk * 32 + kh * 8];
                accs[nb] = __builtin_amdgcn_mfma_f32_16x16x32_bf16(qf[kk], kf, accs[nb], 0, 0, 0);
            }
        }

        float ps[4][4];
        #pragma unroll
        for (int r = 0; r < 4; ++r) {
            float v = fmaxf(fmaxf(accs[0][r], accs[1][r]), fmaxf(accs[2][r], accs[3][r]));
            #pragma unroll
            for (int mk = 1; mk < 16; mk <<= 1) v = fmaxf(v, __shfl_xor(v, mk));
            const float mnew  = fmaxf(mrun[r], v);
            const float alpha = __expf(mrun[r] - mnew);
            mrun[r] = mnew;
            float rs = 0.0f;
            #pragma unroll
            for (int nb = 0; nb < 4; ++nb) {
                const float p = __expf(accs[nb][r] - mnew);
                ps[nb][r] = p;
                rs += p;
            }
            #pragma unroll
            for (int mk = 1; mk < 16; mk <<= 1) rs += __shfl_xor(rs, mk);
            lrun[r] = lrun[r] * alpha + rs;
            #pragma unroll
            for (int db = 0; db < 8; ++db) acc_o[db][r] *= alpha;
        }

        #pragma unroll
        for (int nb = 0; nb < 4; ++nb)
            #pragma unroll
            for (int r = 0; r < 4; ++r)
                Psh[wv][(kh * 4 + r) * PSTR + nb * 16 + lq] = f2bf(ps[nb][r]);

        #pragma unroll
        for (int ks = 0; ks < 2; ++ks) {
            bf16x8 pa = *(const bf16x8*)&Psh[wv][lq * PSTR + ks * 32 + kh * 8];
            #pragma unroll
            for (int db = 0; db < 8; ++db) {
                bf16x8 vf = *(const bf16x8*)&Vsh[(db * 16 + lq) * 72 + ks * 32 + kh * 8];
                acc_o[db] = __builtin_amdgcn_mfma_f32_16x16x32_bf16(pa, vf, acc_o[db], 0, 0, 0);
            }
        }
    }

    #pragma unroll
    for (int r = 0; r < 4; ++r) {
        const float inv = 1.0f / lrun[r];
        float* orow = O + base + (size_t)(q0 + wv * 16 + kh * 4 + r) * DHEAD;
        #pragma unroll
        for (int db = 0; db < 8; ++db)
            orow[db * 16 + lq] = acc_o[db][r] * inv;
    }
}

extern "C" void kernel_launch(void* const* d_in, const int* in_sizes, int n_in,
                              void* d_out, int out_size, void* d_ws, size_t ws_size,
                              hipStream_t stream) {
    const float* Q = (const float*)d_in[0];
    const float* K = (const float*)d_in[1];
    const float* V = (const float*)d_in[2];
    float* O = (float*)d_out;
    const int BH = in_sizes[0] / (SREF * DHEAD);
    const size_t nel = (size_t)BH * SREF * DHEAD;

    if (ws_size >= 2 * nel * sizeof(ushort)) {
        ushort* Kb  = (ushort*)d_ws;
        ushort* VTb = Kb + nel;
        preconv_kernel<<<dim3(SREF / KVBLK, BH), NTHREADS, 0, stream>>>(K, V, Kb, VTb);
        attn_fwd_kernel<<<dim3(SREF / QBLK, BH), NTHREADS, 0, stream>>>(Q, Kb, VTb, O);
    } else {
        attn_fwd_fallback<<<dim3(SREF / QBLK, BH), NTHREADS, 0, stream>>>(Q, K, V, O);
    }
}

// Round 3
// 100.745 us; speedup vs baseline: 4.5820x; 1.8869x over previous
//
#include <hip/hip_runtime.h>
#include <hip/hip_bf16.h>

#define SREF 2048
#define DHEAD 128
#define KVBLK 64
#define NTHREADS 256
#define NTILES (SREF / KVBLK)
#define PSTR 72
#define QSCALE 0.12751743f   /* log2(e)/sqrt(128) */
#define THRLOG 8.0f          /* defer-max threshold, log2 domain */

typedef short bf16x8 __attribute__((ext_vector_type(8)));
typedef float f32x4 __attribute__((ext_vector_type(4)));
typedef float f32x16 __attribute__((ext_vector_type(16)));

typedef const __attribute__((address_space(1))) void* gas_t;
typedef __attribute__((address_space(3))) void* las_t;

__device__ __forceinline__ ushort f2bf(float x) {
    unsigned u = __builtin_bit_cast(unsigned, x);
    u += 0x7fffu + ((u >> 16) & 1u);
    return (ushort)(u >> 16);
}

__device__ __forceinline__ float fexp2(float x) {
#if __has_builtin(__builtin_amdgcn_exp2f)
    return __builtin_amdgcn_exp2f(x);
#else
    return exp2f(x);
#endif
}

__device__ __forceinline__ unsigned cvtpk(float lo, float hi) {
    unsigned r;
    asm("v_cvt_pk_bf16_f32 %0, %1, %2" : "=v"(r) : "v"(lo), "v"(hi));
    return r;   // [15:0]=bf16(lo), [31:16]=bf16(hi)
}

// ---------------- precompute: K -> bf16, V -> V^T bf16 ----------------
__global__ __launch_bounds__(NTHREADS) void preconv_kernel(
    const float* __restrict__ K, const float* __restrict__ V,
    ushort* __restrict__ Kb, ushort* __restrict__ VTb)
{
    __shared__ ushort T[DHEAD * PSTR];
    const int t  = threadIdx.x;
    const int bh = blockIdx.y;
    const int s0 = blockIdx.x * KVBLK;
    const size_t base = (size_t)bh * SREF * DHEAD;

    const float* kb = K + base + (size_t)s0 * DHEAD;
    ushort* kout = Kb + base + (size_t)s0 * DHEAD;
    #pragma unroll
    for (int i = 0; i < 8; ++i) {
        int idx = t + i * NTHREADS;
        float4 f = *(const float4*)(kb + idx * 4);
        ushort4 h; h.x = f2bf(f.x); h.y = f2bf(f.y); h.z = f2bf(f.z); h.w = f2bf(f.w);
        *(ushort4*)(kout + idx * 4) = h;
    }

    const float* vb = V + base + (size_t)s0 * DHEAD;
    #pragma unroll
    for (int i = 0; i < 8; ++i) {
        const int key = (t & 31) + 32 * (i & 1);
        const int d4  = (t >> 5) + 8 * (i >> 1);
        float4 f = *(const float4*)(vb + key * DHEAD + d4 * 4);
        T[(d4 * 4 + 0) * PSTR + key] = f2bf(f.x);
        T[(d4 * 4 + 1) * PSTR + key] = f2bf(f.y);
        T[(d4 * 4 + 2) * PSTR + key] = f2bf(f.z);
        T[(d4 * 4 + 3) * PSTR + key] = f2bf(f.w);
    }
    __syncthreads();

    ushort* vt = VTb + (size_t)bh * DHEAD * SREF + s0;
    #pragma unroll
    for (int i = 0; i < 4; ++i) {
        int idx = t + i * NTHREADS;
        int d = idx >> 3;
        int c = (idx & 7) * 8;
        bf16x8 v = *(const bf16x8*)&T[d * PSTR + c];
        *(bf16x8*)(vt + (size_t)d * SREF + c) = v;
    }
}

// ---------------- main attention kernel: 4 waves x 32 q-rows, 32x32 MFMA ----------------
// LDS map: K tile buf b at [b*16384, +16KB); V^T tile buf b at [32768+b*16384, +16KB)
// epilogue (after final barrier): wave wv O-transpose region at [wv*16896, +16.5KB)
__global__ __launch_bounds__(NTHREADS, 2) void attn_fwd_kernel(
    const float* __restrict__ Q, const ushort* __restrict__ Kb,
    const ushort* __restrict__ VTb, float* __restrict__ O)
{
    __shared__ __align__(16) char smem[67584];

    const int t    = threadIdx.x;
    const int lane = t & 63;
    const int wv   = t >> 6;
    const int hi   = lane >> 5;   // half-wave: selects k-range of A/B frags
    const int q5   = lane & 31;   // q (B-col) / row-in-block index
    const int swz  = (lane & 7) << 4;

    const int bh = blockIdx.y;
    const int q0 = blockIdx.x * 128;
    const size_t base = (size_t)bh * SREF * DHEAD;

    // ---- Q B-fragments: lane holds Q[q=q5][d = dk*16 + hi*8 + j], log2-scaled ----
    bf16x8 qf[8];
    {
        const float* qrow = Q + base + (size_t)(q0 + wv * 32 + q5) * DHEAD;
        #pragma unroll
        for (int dk = 0; dk < 8; ++dk) {
            const int d0 = dk * 16 + hi * 8;
            float4 a = *(const float4*)(qrow + d0);
            float4 b = *(const float4*)(qrow + d0 + 4);
            bf16x8 f;
            f[0] = (short)f2bf(a.x * QSCALE); f[1] = (short)f2bf(a.y * QSCALE);
            f[2] = (short)f2bf(a.z * QSCALE); f[3] = (short)f2bf(a.w * QSCALE);
            f[4] = (short)f2bf(b.x * QSCALE); f[5] = (short)f2bf(b.y * QSCALE);
            f[6] = (short)f2bf(b.z * QSCALE); f[7] = (short)f2bf(b.w * QSCALE);
            qf[dk] = f;
        }
    }

    const char* ksrcb = (const char*)(Kb + base);
    const char* vsrcb = (const char*)(VTb + (size_t)bh * DHEAD * SREF);

    // per-lane swizzled LDS read bases (both-sides XOR swizzle, involution)
    const int kbaseL = q5 * 256 + ((hi * 16) ^ swz);   // K tile: row=key(256B), col=d
    const int vbaseL = q5 * 128 + ((hi * 16) ^ swz);   // V^T tile: row=d(128B), col=key

#define STAGE(b, kv0) do {                                                      \
    const char* kt_ = ksrcb + (size_t)(kv0) * (DHEAD * 2);                      \
    const char* vt_ = vsrcb + (size_t)(kv0) * 2;                                \
    _Pragma("unroll")                                                           \
    for (int i_ = 0; i_ < 4; ++i_) {                                            \
        int L_ = t * 16 + i_ * 4096;                                            \
        int r_ = L_ >> 8;                                                       \
        __builtin_amdgcn_global_load_lds(                                       \
            (gas_t)(const void*)(kt_ + (L_ ^ ((r_ & 7) << 4))),                 \
            (las_t)(void*)(smem + (b) * 16384 + L_), 16, 0, 0);                 \
    }                                                                           \
    _Pragma("unroll")                                                           \
    for (int i_ = 0; i_ < 4; ++i_) {                                            \
        int L_ = t * 16 + i_ * 4096;                                            \
        int d_ = L_ >> 7;                                                       \
        int c_ = L_ & 127;                                                      \
        __builtin_amdgcn_global_load_lds(                                       \
            (gas_t)(const void*)(vt_ + (size_t)d_ * (SREF * 2) + (c_ ^ ((d_ & 7) << 4))), \
            (las_t)(void*)(smem + 32768 + (b) * 16384 + L_), 16, 0, 0);         \
    }                                                                           \
} while (0)

    float mrun = -1e30f, lsum = 0.0f;
    f32x16 acc[4];
    #pragma unroll
    for (int db = 0; db < 4; ++db)
        #pragma unroll
        for (int i = 0; i < 16; ++i) acc[db][i] = 0.0f;

    STAGE(0, 0);
    int buf = 0;

    for (int tt = 0; tt < NTILES; ++tt) {
        if (tt + 1 < NTILES) {
            STAGE(buf ^ 1, (tt + 1) * KVBLK);
            asm volatile("s_waitcnt vmcnt(8)" ::: "memory");
        } else {
            asm volatile("s_waitcnt vmcnt(0)" ::: "memory");
        }
        __builtin_amdgcn_s_barrier();
        __builtin_amdgcn_sched_barrier(0);

        const int kO = buf * 16384;
        const int vO = 32768 + buf * 16384;

        // ---- S^T = K Q^T : lane gets P-row for q=q5, keys kb*32+crow(r,hi) ----
        f32x16 s0, s1;
        #pragma unroll
        for (int i = 0; i < 16; ++i) { s0[i] = 0.0f; s1[i] = 0.0f; }
        __builtin_amdgcn_s_setprio(1);
        #pragma unroll
        for (int dk = 0; dk < 8; ++dk) {
            bf16x8 kf0 = *(const bf16x8*)(smem + kO + (kbaseL ^ (dk << 5)));
            s0 = __builtin_amdgcn_mfma_f32_32x32x16_bf16(kf0, qf[dk], s0, 0, 0, 0);
            bf16x8 kf1 = *(const bf16x8*)(smem + kO + 8192 + (kbaseL ^ (dk << 5)));
            s1 = __builtin_amdgcn_mfma_f32_32x32x16_bf16(kf1, qf[dk], s1, 0, 0, 0);
        }
        __builtin_amdgcn_s_setprio(0);

        // ---- online softmax (base-2), row q=q5 fully lane-local + 1 shfl ----
        float pmax = s0[0];
        #pragma unroll
        for (int i = 1; i < 16; ++i) pmax = fmaxf(pmax, s0[i]);
        #pragma unroll
        for (int i = 0; i < 16; ++i) pmax = fmaxf(pmax, s1[i]);
        pmax = fmaxf(pmax, __shfl_xor(pmax, 32));

        if (!__all(pmax <= mrun + THRLOG)) {
            const float mnew  = fmaxf(mrun, pmax);
            const float alpha = fexp2(mrun - mnew);
            mrun = mnew;
            lsum *= alpha;
            #pragma unroll
            for (int db = 0; db < 4; ++db)
                #pragma unroll
                for (int i = 0; i < 16; ++i) acc[db][i] *= alpha;
        }

        float rs = 0.0f;
        #pragma unroll
        for (int i = 0; i < 16; ++i) { s0[i] = fexp2(s0[i] - mrun); rs += s0[i]; }
        #pragma unroll
        for (int i = 0; i < 16; ++i) { s1[i] = fexp2(s1[i] - mrun); rs += s1[i]; }
        rs += __shfl_xor(rs, 32);
        lsum += rs;

        // ---- P -> A-side bf16 frags in-register (cvt_pk + permlane32_swap) ----
        bf16x8 pa[4];
        #pragma unroll
        for (int kb = 0; kb < 2; ++kb) {
            #pragma unroll
            for (int c = 0; c < 2; ++c) {
                float p0 = (kb ? s1[8*c+0] : s0[8*c+0]);
                float p1 = (kb ? s1[8*c+1] : s0[8*c+1]);
                float p2 = (kb ? s1[8*c+2] : s0[8*c+2]);
                float p3 = (kb ? s1[8*c+3] : s0[8*c+3]);
                float p4 = (kb ? s1[8*c+4] : s0[8*c+4]);
                float p5 = (kb ? s1[8*c+5] : s0[8*c+5]);
                float p6 = (kb ? s1[8*c+6] : s0[8*c+6]);
                float p7 = (kb ? s1[8*c+7] : s0[8*c+7]);
                unsigned x0 = cvtpk(p0, p1);
                unsigned x1 = cvtpk(p2, p3);
                unsigned y0 = cvtpk(p4, p5);
                unsigned y1 = cvtpk(p6, p7);
                asm volatile("v_permlane32_swap_b32 %0, %1" : "+v"(x0), "+v"(y0));
                asm volatile("v_permlane32_swap_b32 %0, %1" : "+v"(x1), "+v"(y1));
                union { unsigned u[4]; bf16x8 v; } U;
                U.u[0] = x0; U.u[1] = x1; U.u[2] = y0; U.u[3] = y1;
                pa[kb * 2 + c] = U.v;
            }
        }

        // ---- O^T += V^T P^T : lane gets O^T[d=32db+crow][q=q5] ----
        __builtin_amdgcn_s_setprio(1);
        #pragma unroll
        for (int db = 0; db < 4; ++db) {
            #pragma unroll
            for (int ks = 0; ks < 4; ++ks) {
                bf16x8 vf = *(const bf16x8*)(smem + vO + db * 4096 + (vbaseL ^ (ks << 5)));
                acc[db] = __builtin_amdgcn_mfma_f32_32x32x16_bf16(vf, pa[ks], acc[db], 0, 0, 0);
            }
        }
        __builtin_amdgcn_s_setprio(0);

        __builtin_amdgcn_sched_barrier(0);
        __builtin_amdgcn_s_barrier();
        buf ^= 1;
    }

    // ---- epilogue: transpose O^T -> O via per-wave LDS, then coalesced store ----
    __syncthreads();   // staging buffers dead; safe to overwrite with O tiles

    const float inv = 1.0f / lsum;
    const int eb = wv * 16896;   // 32 rows x 528B
    #pragma unroll
    for (int db = 0; db < 4; ++db) {
        #pragma unroll
        for (int c = 0; c < 4; ++c) {
            f32x4 v;
            v[0] = acc[db][4*c+0] * inv;
            v[1] = acc[db][4*c+1] * inv;
            v[2] = acc[db][4*c+2] * inv;
            v[3] = acc[db][4*c+3] * inv;
            // d = 32*db + 8*c + 4*hi + e  (e=0..3 contiguous)
            *(f32x4*)(smem + eb + q5 * 528 + db * 128 + c * 32 + hi * 16) = v;
        }
    }
    // wave-private region: lgkmcnt ordering suffices, no barrier
    #pragma unroll
    for (int i = 0; i < 16; ++i) {
        const int flat  = lane + i * 64;
        const int row   = flat >> 5;
        const int chunk = flat & 31;
        f32x4 v = *(const f32x4*)(smem + eb + row * 528 + chunk * 16);
        *(f32x4*)(O + base + (size_t)(q0 + wv * 32 + row) * DHEAD + chunk * 4) = v;
    }
#undef STAGE
}

// ---------------- fallback (known-correct R1 structure; used only if ws too small) ----------------
__global__ __launch_bounds__(NTHREADS) void attn_fwd_fallback(
    const float* __restrict__ Q, const float* __restrict__ K,
    const float* __restrict__ V, float* __restrict__ O)
{
    __shared__ ushort Ksh[KVBLK * 136];
    __shared__ ushort Vsh[DHEAD * 72];
    __shared__ ushort Psh[4][16 * PSTR];

    const int t    = threadIdx.x;
    const int lane = t & 63;
    const int wv   = t >> 6;
    const int lq   = lane & 15;
    const int kh   = lane >> 4;

    const int bh = blockIdx.y;
    const int q0 = blockIdx.x * 64;
    const size_t base = (size_t)bh * SREF * DHEAD;

    const float scale = 0.08838834764831845f;
    bf16x8 qf[4];
    {
        const float* qrow = Q + base + (size_t)(q0 + wv * 16 + lq) * DHEAD;
        #pragma unroll
        for (int kk = 0; kk < 4; ++kk) {
            const int d0 = kk * 32 + kh * 8;
            float4 a = *(const float4*)(qrow + d0);
            float4 b = *(const float4*)(qrow + d0 + 4);
            bf16x8 f;
            f[0] = (short)f2bf(a.x * scale); f[1] = (short)f2bf(a.y * scale);
            f[2] = (short)f2bf(a.z * scale); f[3] = (short)f2bf(a.w * scale);
            f[4] = (short)f2bf(b.x * scale); f[5] = (short)f2bf(b.y * scale);
            f[6] = (short)f2bf(b.z * scale); f[7] = (short)f2bf(b.w * scale);
            qf[kk] = f;
        }
    }

    float mrun[4], lrun[4];
    f32x4 acc_o[8];
    #pragma unroll
    for (int r = 0; r < 4; ++r) { mrun[r] = -1e30f; lrun[r] = 0.0f; }
    #pragma unroll
    for (int db = 0; db < 8; ++db) acc_o[db] = (f32x4){0.f, 0.f, 0.f, 0.f};

    for (int kv0 = 0; kv0 < SREF; kv0 += KVBLK) {
        __syncthreads();
        const float* kbase = K + base + (size_t)kv0 * DHEAD;
        #pragma unroll
        for (int i = 0; i < 8; ++i) {
            const int idx = t + i * NTHREADS;
            const int row = idx >> 5;
            const int c4  = idx & 31;
            float4 f = *(const float4*)(kbase + row * DHEAD + c4 * 4);
            ushort4 h;
            h.x = f2bf(f.x); h.y = f2bf(f.y); h.z = f2bf(f.z); h.w = f2bf(f.w);
            *(ushort4*)&Ksh[row * 136 + c4 * 4] = h;
        }
        const float* vbase = V + base + (size_t)kv0 * DHEAD;
        #pragma unroll
        for (int i = 0; i < 8; ++i) {
            const int key = (t & 31) + 32 * (i & 1);
            const int d4  = (t >> 5) + 8 * (i >> 1);
            float4 f = *(const float4*)(vbase + key * DHEAD + d4 * 4);
            Vsh[(d4 * 4 + 0) * 72 + key] = f2bf(f.x);
            Vsh[(d4 * 4 + 1) * 72 + key] = f2bf(f.y);
            Vsh[(d4 * 4 + 2) * 72 + key] = f2bf(f.z);
            Vsh[(d4 * 4 + 3) * 72 + key] = f2bf(f.w);
        }
        __syncthreads();

        f32x4 accs[4];
        #pragma unroll
        for (int nb = 0; nb < 4; ++nb) accs[nb] = (f32x4){0.f, 0.f, 0.f, 0.f};
        #pragma unroll
        for (int kk = 0; kk < 4; ++kk) {
            #pragma unroll
            for (int nb = 0; nb < 4; ++nb) {
                bf16x8 kf = *(const bf16x8*)&Ksh[(nb * 16 + lq) * 136 + kk * 32 + kh * 8];
                accs[nb] = __builtin_amdgcn_mfma_f32_16x16x32_bf16(qf[kk], kf, accs[nb], 0, 0, 0);
            }
        }

        float ps[4][4];
        #pragma unroll
        for (int r = 0; r < 4; ++r) {
            float v = fmaxf(fmaxf(accs[0][r], accs[1][r]), fmaxf(accs[2][r], accs[3][r]));
            #pragma unroll
            for (int mk = 1; mk < 16; mk <<= 1) v = fmaxf(v, __shfl_xor(v, mk));
            const float mnew  = fmaxf(mrun[r], v);
            const float alpha = __expf(mrun[r] - mnew);
            mrun[r] = mnew;
            float rs = 0.0f;
            #pragma unroll
            for (int nb = 0; nb < 4; ++nb) {
                const float p = __expf(accs[nb][r] - mnew);
                ps[nb][r] = p;
                rs += p;
            }
            #pragma unroll
            for (int mk = 1; mk < 16; mk <<= 1) rs += __shfl_xor(rs, mk);
            lrun[r] = lrun[r] * alpha + rs;
            #pragma unroll
            for (int db = 0; db < 8; ++db) acc_o[db][r] *= alpha;
        }

        #pragma unroll
        for (int nb = 0; nb < 4; ++nb)
            #pragma unroll
            for (int r = 0; r < 4; ++r)
                Psh[wv][(kh * 4 + r) * PSTR + nb * 16 + lq] = f2bf(ps[nb][r]);

        #pragma unroll
        for (int ks = 0; ks < 2; ++ks) {
            bf16x8 pa = *(const bf16x8*)&Psh[wv][lq * PSTR + ks * 32 + kh * 8];
            #pragma unroll
            for (int db = 0; db < 8; ++db) {
                bf16x8 vf = *(const bf16x8*)&Vsh[(db * 16 + lq) * 72 + ks * 32 + kh * 8];
                acc_o[db] = __builtin_amdgcn_mfma_f32_16x16x32_bf16(pa, vf, acc_o[db], 0, 0, 0);
            }
        }
    }

    #pragma unroll
    for (int r = 0; r < 4; ++r) {
        const float inv = 1.0f / lrun[r];
        float* orow = O + base + (size_t)(q0 + wv * 16 + kh * 4 + r) * DHEAD;
        #pragma unroll
        for (int db = 0; db < 8; ++db)
            orow[db * 16 + lq] = acc_o[db][r] * inv;
    }
}

extern "C" void kernel_launch(void* const* d_in, const int* in_sizes, int n_in,
                              void* d_out, int out_size, void* d_ws, size_t ws_size,
                              hipStream_t stream) {
    const float* Q = (const float*)d_in[0];
    const float* K = (const float*)d_in[1];
    const float* V = (const float*)d_in[2];
    float* O = (float*)d_out;
    const int BH = in_sizes[0] / (SREF * DHEAD);
    const size_t nel = (size_t)BH * SREF * DHEAD;

    if (ws_size >= 2 * nel * sizeof(ushort)) {
        ushort* Kb  = (ushort*)d_ws;
        ushort* VTb = Kb + nel;
        preconv_kernel<<<dim3(SREF / KVBLK, BH), NTHREADS, 0, stream>>>(K, V, Kb, VTb);
        attn_fwd_kernel<<<dim3(SREF / 128, BH), NTHREADS, 0, stream>>>(Q, Kb, VTb, O);
    } else {
        attn_fwd_fallback<<<dim3(SREF / 64, BH), NTHREADS, 0, stream>>>(Q, K, V, O);
    }
}